// Round 10
// baseline (3939.895 us; speedup 1.0000x reference)
//
#include <hip/hip_runtime.h>

// Weight-stationary pipelined stacked-LSTM, v10: group-interleaved latency hiding.
// 16 teams x 5 blocks (80 blocks, 256 thr): role 0 = front (L1+L2+LIN),
// roles 1-4 = L3 quarters (1 tile/wave = 192 weight VGPRs, no spill).
// Each team owns 4 groups of 16 batches; blocks sweep groups each step with
// register double-buffered prefetch -> MALL hop latency hidden under other
// groups' compute. Per-wave flags, one poll per sweep, no barriers in quarter
// main phase. System-scope relaxed atomics (R5-proven) + watchdog.

#define T_SEQ 256
#define NTEAM 16
#define G4 4
#define DEPTH 4

#define NJT1 4
#define NJT2 8
#define NJT3 16
#define NKB1 3
#define NKB2 6
#define NKB3 12
#define WSZ1 (NJT1*4*NKB1*512)   // 24576 halfs
#define WSZ2 (NJT2*4*NKB2*512)   // 98304
#define WSZ3 (NJT3*4*NKB3*512)   // 393216
#define WTOT (WSZ1+WSZ2+WSZ3)    // 516096 halfs

#define H2_TEAM (G4*DEPTH*2048)  // halfs
#define H3_TEAM (G4*DEPTH*4096)
#define PR_TEAM (G4*DEPTH*4*32)  // floats
#define FL_TEAM 1088             // ints (17 flags x 64)
#define CAP_WAIT (1<<22)

typedef _Float16 half8 __attribute__((ext_vector_type(8)));
typedef _Float16 half4 __attribute__((ext_vector_type(4)));
typedef float f32x4 __attribute__((ext_vector_type(4)));

union H4u { unsigned long long u; half4 h; };
union H8u { unsigned long long u[2]; half8 h; };

__device__ __forceinline__ float sigm(float x) {
  return __fdividef(1.f, 1.f + __expf(-x));
}
__device__ __forceinline__ float tanh_fast(float x) {
  float t = __expf(-2.f * fabsf(x));
  float r = __fdividef(1.f - t, 1.f + t);
  return copysignf(r, x);
}

__device__ __forceinline__ unsigned long long ld64p(const _Float16* p) {
  return __hip_atomic_load((const unsigned long long*)p, __ATOMIC_RELAXED,
                           __HIP_MEMORY_SCOPE_SYSTEM);
}
__device__ __forceinline__ void st64p(_Float16* p, half4 v) {
  H4u r; r.h = v;
  __hip_atomic_store((unsigned long long*)p, r.u, __ATOMIC_RELAXED,
                     __HIP_MEMORY_SCOPE_SYSTEM);
}
__device__ __forceinline__ float ldfp(const float* p) {
  return __hip_atomic_load(p, __ATOMIC_RELAXED, __HIP_MEMORY_SCOPE_SYSTEM);
}
__device__ __forceinline__ void stfp(float* p, float v) {
  __hip_atomic_store(p, v, __ATOMIC_RELAXED, __HIP_MEMORY_SCOPE_SYSTEM);
}
__device__ __forceinline__ void stflag(int* p, int v) {
  __hip_atomic_store(p, v, __ATOMIC_RELAXED, __HIP_MEMORY_SCOPE_SYSTEM);
}
__device__ __forceinline__ void vm0() {
  asm volatile("s_waitcnt vmcnt(0)" ::: "memory");
}
// lanes 0-15 poll fl3[lane] >= tg3; lane 16 polls flf >= tgF; others pass
__device__ __forceinline__ void waitq(const int* ft, int tg3, int tgF, int* dead) {
  if (*dead) return;
  const int lane = threadIdx.x & 63;
  const int* p = ft + ((lane < 17) ? lane : 0) * 64;
  const int tg = (lane < 16) ? tg3 : (lane == 16 ? tgF : (int)0x80000000);
  int it = 0;
  while (true) {
    const int v = __hip_atomic_load(p, __ATOMIC_RELAXED, __HIP_MEMORY_SCOPE_SYSTEM);
    if (__all(v >= tg)) break;
    if (++it > CAP_WAIT) { *dead = 1; break; }
    __builtin_amdgcn_s_sleep(1);
  }
  asm volatile("" ::: "memory");
}

// ---- prep: fp32 weights -> f16 MFMA A-fragment layout (verified R2-R9) --------
__global__ void prep_weights(const float* __restrict__ Wih1, const float* __restrict__ Whh1,
                             const float* __restrict__ Wih2, const float* __restrict__ Whh2,
                             const float* __restrict__ Wih3, const float* __restrict__ Whh3,
                             _Float16* __restrict__ WT) {
  int idx = blockIdx.x * blockDim.x + threadIdx.x;
  if (idx >= WTOT) return;
  float v = 0.f;
  if (idx < WSZ1) {
    const int e = idx, blk = e >> 9, wb = e & 511;
    const int lane = wb >> 3, j = wb & 7;
    const int tl = blk / NKB1, kk = blk % NKB1;
    const int q = tl / NJT1, jt = tl % NJT1;
    const int r = q * 64 + jt * 16 + (lane & 15);
    const int k = kk * 32 + ((lane >> 4) << 3) + j;
    if (k < 64)       v = Whh1[r * 64 + k];
    else if (k < 66)  v = Wih1[r * 2 + (k - 64)];
  } else if (idx < WSZ1 + WSZ2) {
    const int e = idx - WSZ1, blk = e >> 9, wb = e & 511;
    const int lane = wb >> 3, j = wb & 7;
    const int tl = blk / NKB2, kk = blk % NKB2;
    const int q = tl / NJT2, jt = tl % NJT2;
    const int r = q * 128 + jt * 16 + (lane & 15);
    const int k = kk * 32 + ((lane >> 4) << 3) + j;
    if (k < 64)       v = Wih2[r * 64 + k];
    else              v = Whh2[r * 128 + (k - 64)];
  } else {
    const int e = idx - WSZ1 - WSZ2, blk = e >> 9, wb = e & 511;
    const int lane = wb >> 3, j = wb & 7;
    const int tl = blk / NKB3, kk = blk % NKB3;
    const int q = tl / NJT3, jt = tl % NJT3;
    const int r = q * 256 + jt * 16 + (lane & 15);
    const int k = kk * 32 + ((lane >> 4) << 3) + j;
    if (k < 128)      v = Wih3[r * 128 + k];
    else              v = Whh3[r * 256 + (k - 128)];
  }
  WT[idx] = (_Float16)v;
}

// quarter-group load: h2(g,t) + h3(g,t-1) -> bf[12]
#define LOADQ(bf, g, t)                                                        \
  {                                                                            \
    const _Float16* p2_ = h2b + (((g)*DEPTH + ((t)&3)) << 11) + n*128 + l4*8;  \
    _Pragma("unroll")                                                          \
    for (int kk_ = 0; kk_ < 4; ++kk_) {                                        \
      H8u u_; u_.u[0] = ld64p(p2_ + kk_*32); u_.u[1] = ld64p(p2_ + kk_*32 + 4);\
      bf[kk_] = u_.h;                                                          \
    }                                                                          \
    if ((t) > 0) {                                                             \
      const _Float16* p3_ = h3b + (((g)*DEPTH + (((t)-1)&3)) << 12)            \
                          + n*256 + l4*8;                                      \
      _Pragma("unroll")                                                        \
      for (int s_ = 0; s_ < 8; ++s_) {                                         \
        H8u u_; u_.u[0] = ld64p(p3_ + s_*32); u_.u[1] = ld64p(p3_ + s_*32 + 4);\
        bf[4 + s_] = u_.h;                                                     \
      }                                                                        \
    } else {                                                                   \
      _Pragma("unroll")                                                        \
      for (int s_ = 0; s_ < 8; ++s_) bf[4 + s_] = half8{};                     \
    }                                                                          \
  }

#define COMPUTEQ(bf, g, t, futp)                                               \
  {                                                                            \
    f32x4 acc_[4];                                                             \
    _Pragma("unroll")                                                          \
    for (int q_ = 0; q_ < 4; ++q_)                                             \
      _Pragma("unroll")                                                        \
      for (int e_ = 0; e_ < 4; ++e_) acc_[q_][e_] = b3r[q_][e_];               \
    _Pragma("unroll")                                                          \
    for (int q_ = 0; q_ < 4; ++q_)                                             \
      _Pragma("unroll")                                                        \
      for (int kk_ = 0; kk_ < 12; ++kk_)                                       \
        acc_[q_] = __builtin_amdgcn_mfma_f32_16x16x32_f16(a3[q_][kk_], bf[kk_],\
                                                          acc_[q_], 0, 0, 0); \
    half4 hv_; float hf_[4];                                                   \
    _Pragma("unroll")                                                          \
    for (int e_ = 0; e_ < 4; ++e_) {                                           \
      const float cn_ = sigm(acc_[1][e_]) * c3[g][e_]                          \
                      + sigm(acc_[0][e_]) * tanh_fast(acc_[2][e_]);            \
      hf_[e_] = sigm(acc_[3][e_]) * tanh_fast(cn_);                            \
      c3[g][e_] = cn_;                                                         \
      hv_[e_] = (_Float16)hf_[e_];                                             \
    }                                                                          \
    st64p(h3b + (((g)*DEPTH + ((t)&3)) << 12) + n*256 + tl*16 + l4*4, hv_);    \
    if (futp) {                                                                \
      float p0_ = 0.f, p1_ = 0.f;                                              \
      _Pragma("unroll")                                                        \
      for (int e_ = 0; e_ < 4; ++e_) {                                         \
        p0_ = fmaf(wle[0][e_], hf_[e_], p0_);                                  \
        p1_ = fmaf(wle[1][e_], hf_[e_], p1_);                                  \
      }                                                                        \
      part[g][n][0][(w << 2) | l4] = p0_;                                      \
      part[g][n][1][(w << 2) | l4] = p1_;                                      \
    }                                                                          \
  }

__global__ __launch_bounds__(256, 1) void pipe_main(
    const float* __restrict__ input, const int* __restrict__ future_p,
    const float* __restrict__ bih1, const float* __restrict__ bhh1,
    const float* __restrict__ bih2, const float* __restrict__ bhh2,
    const float* __restrict__ bih3, const float* __restrict__ bhh3,
    const float* __restrict__ Wlin, const float* __restrict__ blin,
    const _Float16* __restrict__ WT,
    _Float16* __restrict__ h2r, _Float16* __restrict__ h3r,
    float* __restrict__ pr, int* __restrict__ flags,
    float* __restrict__ out) {
  __shared__ __align__(16) _Float16 xh1s[G4][16][104];  // [h1(64)|x(2)|pad]
  __shared__ __align__(16) _Float16 xh2s[G4][16][200];  // [h1(64)|h2(128)|pad]
  __shared__ float wlinF[2][192];
  __shared__ float part[G4][16][2][16];

  const int tid = threadIdx.x;
  const int w = tid >> 6, lane = tid & 63;
  const int n = lane & 15, l4 = lane >> 4;
  const int team = blockIdx.x % NTEAM;
  const int role = blockIdx.x / NTEAM;   // 0 front, 1..4 quarters
  const int b0 = team * 64;
  const int fut = *future_p;
  const int nsteps = T_SEQ - 1 + fut;    // 271
  int* ft = flags + team * FL_TEAM;      // fl3[tl] at ft+tl*64; flf at ft+16*64
  int* flf = ft + 16 * 64;
  _Float16* h2b = h2r + (size_t)team * H2_TEAM;
  _Float16* h3b = h3r + (size_t)team * H3_TEAM;
  float* prb = pr + (size_t)team * PR_TEAM;
  int dead = 0;
  const int NEG = (int)0x80000000;

  if (role == 0) {
    // =================== front: L1 + L2 + LIN ===================
    for (int i = tid; i < G4*16*104; i += 256) (&xh1s[0][0][0])[i] = (_Float16)0.f;
    for (int i = tid; i < G4*16*200; i += 256) (&xh2s[0][0][0])[i] = (_Float16)0.f;
    for (int i = tid; i < 384; i += 256)
      wlinF[i / 192][i % 192] = Wlin[(i / 192) * 448 + (i % 192)];

    half8 a1[4][3];
#pragma unroll
    for (int q = 0; q < 4; ++q)
#pragma unroll
      for (int kk = 0; kk < 3; ++kk)
        a1[q][kk] = *(const half8*)(WT + ((q*NJT1 + w)*NKB1 + kk)*512 + lane*8);
    half8 a2[2][4][6];
#pragma unroll
    for (int u = 0; u < 2; ++u)
#pragma unroll
      for (int q = 0; q < 4; ++q)
#pragma unroll
        for (int kk = 0; kk < 6; ++kk)
          a2[u][q][kk] = *(const half8*)(WT + WSZ1 + ((q*NJT2 + (u*4+w))*NKB2 + kk)*512 + lane*8);
    float b1r[4][4], b2r[2][4][4];
#pragma unroll
    for (int q = 0; q < 4; ++q)
#pragma unroll
      for (int e = 0; e < 4; ++e) {
        const int r1 = q*64 + w*16 + l4*4 + e;
        b1r[q][e] = bih1[r1] + bhh1[r1];
#pragma unroll
        for (int u = 0; u < 2; ++u) {
          const int r2 = q*128 + (u*4+w)*16 + l4*4 + e;
          b2r[u][q][e] = bih2[r2] + bhh2[r2];
        }
      }
    float c1[G4][4] = {}, c2[2][G4][4] = {};
    __syncthreads();

    for (int it = 0; it <= nsteps; ++it) {
      const int tp = it - 1;
      waitq(ft, (it >= T_SEQ) ? it : it - 3, NEG, &dead);

      // ---- LIN(tp) (future): front 192 cols + quarter partials ----
      if (tp >= T_SEQ - 1 && tid < 128) {
        const int g = tid >> 5, nn = (tid >> 1) & 15, ch = tid & 1;
        float acc = 0.f;
#pragma unroll
        for (int i = 0; i < 48; ++i) {
          const int k = i * 4;
          const half4 xv = *(const half4*)(&xh2s[g][nn][k]);
          const float* wl = &wlinF[ch][k];
          acc = fmaf(wl[0], (float)xv[0], acc);
          acc = fmaf(wl[1], (float)xv[1], acc);
          acc = fmaf(wl[2], (float)xv[2], acc);
          acc = fmaf(wl[3], (float)xv[3], acc);
        }
        const int sl = tp & 3;
#pragma unroll
        for (int q = 0; q < 4; ++q)
          acc += ldfp(prb + ((g*DEPTH + sl)*4 + q)*32 + nn*2 + ch);
        const float o = acc + blin[ch];
        out[((size_t)(b0 + g*16 + nn)*fut + (tp - (T_SEQ - 1)))*2 + ch] = o;
        xh1s[g][nn][64 + ch] = (_Float16)o;
      }
      if (it < T_SEQ && tid < 128) {
        const int g = tid >> 5, nn = (tid >> 1) & 15, ch = tid & 1;
        xh1s[g][nn][64 + ch] =
            (_Float16)input[((size_t)(b0 + g*16 + nn)*T_SEQ + it)*2 + ch];
      }
      if (it == nsteps) break;
      __syncthreads();

      // ---- L1(it) all groups ----
      half8 bf1[G4][3];
#pragma unroll
      for (int g = 0; g < G4; ++g)
#pragma unroll
        for (int kk = 0; kk < 3; ++kk)
          bf1[g][kk] = *(const half8*)(&xh1s[g][n][kk*32 + l4*8]);
      __syncthreads();
#pragma unroll
      for (int g = 0; g < G4; ++g) {
        f32x4 acc[4];
#pragma unroll
        for (int q = 0; q < 4; ++q)
#pragma unroll
          for (int e = 0; e < 4; ++e) acc[q][e] = b1r[q][e];
#pragma unroll
        for (int q = 0; q < 4; ++q)
#pragma unroll
          for (int kk = 0; kk < 3; ++kk)
            acc[q] = __builtin_amdgcn_mfma_f32_16x16x32_f16(a1[q][kk], bf1[g][kk], acc[q], 0, 0, 0);
        half4 hv;
#pragma unroll
        for (int e = 0; e < 4; ++e) {
          const float cn = sigm(acc[1][e]) * c1[g][e] + sigm(acc[0][e]) * tanh_fast(acc[2][e]);
          const float h = sigm(acc[3][e]) * tanh_fast(cn);
          c1[g][e] = cn;
          hv[e] = (_Float16)h;
        }
        *(half4*)(&xh1s[g][n][w*16 + l4*4]) = hv;
        *(half4*)(&xh2s[g][n][w*16 + l4*4]) = hv;
      }
      __syncthreads();

      // ---- L2(it) all groups ----
      half8 bf2[G4][6];
#pragma unroll
      for (int g = 0; g < G4; ++g)
#pragma unroll
        for (int kk = 0; kk < 6; ++kk)
          bf2[g][kk] = *(const half8*)(&xh2s[g][n][kk*32 + l4*8]);
      __syncthreads();
      const int slot = it & 3;
#pragma unroll
      for (int u = 0; u < 2; ++u)
#pragma unroll
        for (int g = 0; g < G4; ++g) {
          f32x4 acc[4];
#pragma unroll
          for (int q = 0; q < 4; ++q)
#pragma unroll
            for (int e = 0; e < 4; ++e) acc[q][e] = b2r[u][q][e];
#pragma unroll
          for (int q = 0; q < 4; ++q)
#pragma unroll
            for (int kk = 0; kk < 6; ++kk)
              acc[q] = __builtin_amdgcn_mfma_f32_16x16x32_f16(a2[u][q][kk], bf2[g][kk], acc[q], 0, 0, 0);
          half4 hv;
#pragma unroll
          for (int e = 0; e < 4; ++e) {
            const float cn = sigm(acc[1][e]) * c2[u][g][e] + sigm(acc[0][e]) * tanh_fast(acc[2][e]);
            const float h = sigm(acc[3][e]) * tanh_fast(cn);
            c2[u][g][e] = cn;
            hv[e] = (_Float16)h;
          }
          const int row = (u*4 + w)*16 + l4*4;
          *(half4*)(&xh2s[g][n][64 + row]) = hv;
          st64p(h2b + ((g*DEPTH + slot) << 11) + n*128 + row, hv);
        }
      vm0();
      __syncthreads();
      if (tid == 0) stflag(flf, it + 1);
    }
  } else {
    // =================== L3 quarter: 1 tile/wave, no main-phase barriers ======
    const int qh = role - 1;
    const int tl = qh*4 + w;              // global tile 0..15
    half8 a3[4][12];
#pragma unroll
    for (int q = 0; q < 4; ++q)
#pragma unroll
      for (int kk = 0; kk < 12; ++kk)
        a3[q][kk] = *(const half8*)(WT + WSZ1 + WSZ2 + ((q*NJT3 + tl)*NKB3 + kk)*512 + lane*8);
    float b3r[4][4], wle[2][4];
#pragma unroll
    for (int q = 0; q < 4; ++q)
#pragma unroll
      for (int e = 0; e < 4; ++e) {
        const int r = q*256 + tl*16 + l4*4 + e;
        b3r[q][e] = bih3[r] + bhh3[r];
      }
#pragma unroll
    for (int ch = 0; ch < 2; ++ch)
#pragma unroll
      for (int e = 0; e < 4; ++e)
        wle[ch][e] = Wlin[ch*448 + 192 + tl*16 + l4*4 + e];
    float c3[G4][4] = {};
    half8 bfA[12], bfB[12];

    for (int t = 0; t < nsteps; ++t) {
      waitq(ft, t, t + 1, &dead);
      const bool futp = (t >= T_SEQ - 1);

      LOADQ(bfA, 0, t);
      LOADQ(bfB, 1, t);
      __builtin_amdgcn_sched_barrier(0);
      COMPUTEQ(bfA, 0, t, futp);
      LOADQ(bfA, 2, t);
      __builtin_amdgcn_sched_barrier(0);
      COMPUTEQ(bfB, 1, t, futp);
      LOADQ(bfB, 3, t);
      __builtin_amdgcn_sched_barrier(0);
      COMPUTEQ(bfA, 2, t, futp);
      COMPUTEQ(bfB, 3, t, futp);

      if (futp) {
        __syncthreads();                  // partials in LDS visible
        if (tid < 128) {
          const int g = tid >> 5, nn = (tid >> 1) & 15, ch = tid & 1;
          float s = 0.f;
#pragma unroll
          for (int j = 0; j < 16; ++j) s += part[g][nn][ch][j];
          stfp(prb + ((g*DEPTH + (t & 3))*4 + qh)*32 + nn*2 + ch, s);
        }
      }
      vm0();                              // per-wave: own stores acked
      if (lane == 0) stflag(ft + tl*64, t + 1);
    }
  }
}

extern "C" void kernel_launch(void* const* d_in, const int* in_sizes, int n_in,
                              void* d_out, int out_size, void* d_ws, size_t ws_size,
                              hipStream_t stream) {
  const float* input = (const float*)d_in[0];
  const int*   fut   = (const int*)d_in[1];
  const float* Wih1  = (const float*)d_in[2];
  const float* Whh1  = (const float*)d_in[3];
  const float* bih1  = (const float*)d_in[4];
  const float* bhh1  = (const float*)d_in[5];
  const float* Wih2  = (const float*)d_in[6];
  const float* Whh2  = (const float*)d_in[7];
  const float* bih2  = (const float*)d_in[8];
  const float* bhh2  = (const float*)d_in[9];
  const float* Wih3  = (const float*)d_in[10];
  const float* Whh3  = (const float*)d_in[11];
  const float* bih3  = (const float*)d_in[12];
  const float* bhh3  = (const float*)d_in[13];
  const float* Wlin  = (const float*)d_in[14];
  const float* blin  = (const float*)d_in[15];
  float* out = (float*)d_out;

  _Float16* WT  = (_Float16*)d_ws;
  _Float16* h2r = WT + WTOT;
  _Float16* h3r = h2r + (size_t)NTEAM * H2_TEAM;
  float*    pr  = (float*)(h3r + (size_t)NTEAM * H3_TEAM);
  int*    flags = (int*)(pr + (size_t)NTEAM * PR_TEAM);
  const size_t flag_bytes = (size_t)NTEAM * FL_TEAM * sizeof(int);

  prep_weights<<<(WTOT + 255) / 256, 256, 0, stream>>>(Wih1, Whh1, Wih2, Whh2, Wih3, Whh3, WT);
  hipMemsetAsync(flags, 0, flag_bytes, stream);
  pipe_main<<<5 * NTEAM, 256, 0, stream>>>(input, fut,
                                           bih1, bhh1, bih2, bhh2, bih3, bhh3,
                                           Wlin, blin, WT, h2r, h3r, pr, flags, out);
}

// Round 11
// 1861.651 us; speedup vs baseline: 2.1163x; 2.1163x over previous
//
#include <hip/hip_runtime.h>

// Weight-stationary pipelined stacked-LSTM, v11 = R5 structure + batched
// pipelined remote loads. 32 teams x 5 blocks (160 blocks, 256 thr):
// role 0 = front (L1+L2+LIN), roles 1-4 = L3 quarters (1 tile/wave).
// Ring data via inline-asm global_load_dwordx4/store_dwordx2 "sc0 sc1"
// (SYSTEM scope, MALL-coherent) batched with ONE vmcnt drain per step.
// Flags via relaxed system atomics (R5-proven). Watchdog-capped polls.

#define T_SEQ 256
#define NTEAM 32
#define DEPTH 8
#define DMASK 7

#define NJT1 4
#define NJT2 8
#define NJT3 16
#define NKB1 3     // K1 = 66 -> padded 96  [h1(64) | x(2) | pad]
#define NKB2 6     // K2 = 192              [h1(64) | h2(128)]
#define NKB3 12    // K3 = 384              [h2(128) | h3(256)]

#define WSZ1 (NJT1*4*NKB1*512)   // 24576 halfs
#define WSZ2 (NJT2*4*NKB2*512)   // 98304
#define WSZ3 (NJT3*4*NKB3*512)   // 393216
#define WTOT (WSZ1+WSZ2+WSZ3)    // 516096 halfs ~ 1.01 MB

#define H2_G    2048             // [16][128] halfs
#define H2_SLOT (2*H2_G)
#define H2_TEAM (DEPTH*H2_SLOT)
#define H3_G    4096             // [16][256] halfs
#define H3_SLOT (2*H3_G)
#define H3_TEAM (DEPTH*H3_SLOT)
#define CAP_WAIT (1<<21)

typedef _Float16 half8 __attribute__((ext_vector_type(8)));
typedef _Float16 half4 __attribute__((ext_vector_type(4)));
typedef float f32x4 __attribute__((ext_vector_type(4)));

__device__ __forceinline__ float sigm(float x) {
  return __fdividef(1.f, 1.f + __expf(-x));
}
__device__ __forceinline__ float tanh_fast(float x) {
  float t = __expf(-2.f * fabsf(x));
  float r = __fdividef(1.f - t, 1.f + t);
  return copysignf(r, x);
}

// ---- system-scope (sc0 sc1 = MALL-coherent) batched data prims ----
__device__ __forceinline__ void ldg16(half8* d, const _Float16* p) {
  asm volatile("global_load_dwordx4 %0, %1, off sc0 sc1"
               : "=v"(*d) : "v"(p) : "memory");
}
__device__ __forceinline__ void stg8(_Float16* p, half4 v) {
  asm volatile("global_store_dwordx2 %0, %1, off sc0 sc1"
               :: "v"(p), "v"(v) : "memory");
}
__device__ __forceinline__ void drain() {
  asm volatile("s_waitcnt vmcnt(0)" ::: "memory");
  __builtin_amdgcn_sched_barrier(0);
}
__device__ __forceinline__ void stflag(int* p, int v) {
  __hip_atomic_store(p, v, __ATOMIC_RELAXED, __HIP_MEMORY_SCOPE_SYSTEM);
}
// lanes 0-3 poll fl3[0..3] >= t3; lane 4 polls flf >= tf; NEG targets pass.
__device__ __forceinline__ void wait_team(const int* fb, int t3, int tf,
                                          volatile int* sdead) {
  if (*sdead) return;
  const int lane = threadIdx.x & 63;
  const int* p = fb + ((lane < 5) ? lane : 0) * 64;
  const int tg = (lane < 4) ? t3 : (lane == 4 ? tf : (int)0x80000000);
  int iter = 0;
  while (true) {
    const int v = __hip_atomic_load(p, __ATOMIC_RELAXED, __HIP_MEMORY_SCOPE_SYSTEM);
    if (__all(v >= tg)) break;
    if (++iter > CAP_WAIT) { if (lane == 0) *sdead = 1; break; }
    __builtin_amdgcn_s_sleep(1);
  }
  asm volatile("" ::: "memory");
}

// ---- prep: fp32 weights -> f16 MFMA A-fragment layout (verified R2-R10) -------
__global__ void prep_weights(const float* __restrict__ Wih1, const float* __restrict__ Whh1,
                             const float* __restrict__ Wih2, const float* __restrict__ Whh2,
                             const float* __restrict__ Wih3, const float* __restrict__ Whh3,
                             _Float16* __restrict__ WT) {
  int idx = blockIdx.x * blockDim.x + threadIdx.x;
  if (idx >= WTOT) return;
  float v = 0.f;
  if (idx < WSZ1) {
    const int e = idx, blk = e >> 9, wb = e & 511;
    const int lane = wb >> 3, j = wb & 7;
    const int tl = blk / NKB1, kk = blk % NKB1;
    const int q = tl / NJT1, jt = tl % NJT1;
    const int r = q * 64 + jt * 16 + (lane & 15);
    const int k = kk * 32 + ((lane >> 4) << 3) + j;
    if (k < 64)       v = Whh1[r * 64 + k];
    else if (k < 66)  v = Wih1[r * 2 + (k - 64)];
  } else if (idx < WSZ1 + WSZ2) {
    const int e = idx - WSZ1, blk = e >> 9, wb = e & 511;
    const int lane = wb >> 3, j = wb & 7;
    const int tl = blk / NKB2, kk = blk % NKB2;
    const int q = tl / NJT2, jt = tl % NJT2;
    const int r = q * 128 + jt * 16 + (lane & 15);
    const int k = kk * 32 + ((lane >> 4) << 3) + j;
    if (k < 64)       v = Wih2[r * 64 + k];
    else              v = Whh2[r * 128 + (k - 64)];
  } else {
    const int e = idx - WSZ1 - WSZ2, blk = e >> 9, wb = e & 511;
    const int lane = wb >> 3, j = wb & 7;
    const int tl = blk / NKB3, kk = blk % NKB3;
    const int q = tl / NJT3, jt = tl % NJT3;
    const int r = q * 256 + jt * 16 + (lane & 15);
    const int k = kk * 32 + ((lane >> 4) << 3) + j;
    if (k < 128)      v = Wih3[r * 128 + k];
    else              v = Whh3[r * 256 + (k - 128)];
  }
  WT[idx] = (_Float16)v;
}

// ---- main pipelined kernel ----------------------------------------------------
__global__ __launch_bounds__(256, 1) void pipe_main(
    const float* __restrict__ input, const int* __restrict__ future_p,
    const float* __restrict__ bih1, const float* __restrict__ bhh1,
    const float* __restrict__ bih2, const float* __restrict__ bhh2,
    const float* __restrict__ bih3, const float* __restrict__ bhh3,
    const float* __restrict__ Wlin, const float* __restrict__ blin,
    const _Float16* __restrict__ WT,
    _Float16* __restrict__ h2r, _Float16* __restrict__ h3r,
    int* __restrict__ flags,
    float* __restrict__ out) {
  __shared__ __align__(16) _Float16 xh1s[2][16][104];  // [h1(64)|x(2)|0pad..96]
  __shared__ __align__(16) _Float16 xh2s[2][16][200];  // [h1(64)|h2(128)|pad]
  __shared__ __align__(16) _Float16 xh3ld[2][16][264]; // LIN h3 staging
  __shared__ float wlin[2][448];
  __shared__ volatile int sh_dead;

  const int fut = *future_p;
  const int nsteps = T_SEQ - 1 + fut;   // 271

  const int team = blockIdx.x & 31;
  const int role = blockIdx.x >> 5;     // 0 front, 1..4 quarters
  const int b0 = team * 32;
  const int NEG = (int)0x80000000;

  int* fb = flags + team * 512;         // fl3[s]=fb+s*64 (s=0..3), flf=fb+4*64
  _Float16* h2b = h2r + (size_t)team * H2_TEAM;
  _Float16* h3b = h3r + (size_t)team * H3_TEAM;

  const int tid = threadIdx.x;
  const int w = tid >> 6, lane = tid & 63;
  const int n = lane & 15, l4 = lane >> 4;
  if (tid == 0) sh_dead = 0;

  if (role == 0) {
    // =================== front: L1 + L2 + LIN ===================
    for (int i = tid; i < 2*16*104; i += 256) (&xh1s[0][0][0])[i] = (_Float16)0.f;
    for (int i = tid; i < 2*16*200; i += 256) (&xh2s[0][0][0])[i] = (_Float16)0.f;
    for (int i = tid; i < 896; i += 256) (&wlin[0][0])[i] = Wlin[i];

    half8 a1[4][3];
#pragma unroll
    for (int q = 0; q < 4; ++q)
#pragma unroll
      for (int kk = 0; kk < 3; ++kk)
        a1[q][kk] = *(const half8*)(WT + ((q*NJT1 + w)*NKB1 + kk)*512 + lane*8);
    half8 a2[2][4][6];
#pragma unroll
    for (int u = 0; u < 2; ++u)
#pragma unroll
      for (int q = 0; q < 4; ++q)
#pragma unroll
        for (int kk = 0; kk < 6; ++kk)
          a2[u][q][kk] = *(const half8*)(WT + WSZ1 + ((q*NJT2 + (u*4+w))*NKB2 + kk)*512 + lane*8);
    float b1r[4][4], b2r[2][4][4];
#pragma unroll
    for (int q = 0; q < 4; ++q)
#pragma unroll
      for (int e = 0; e < 4; ++e) {
        const int r1 = q*64 + w*16 + l4*4 + e;
        b1r[q][e] = bih1[r1] + bhh1[r1];
#pragma unroll
        for (int u = 0; u < 2; ++u) {
          const int r2 = q*128 + (u*4+w)*16 + l4*4 + e;
          b2r[u][q][e] = bih2[r2] + bhh2[r2];
        }
      }
    float c1[2][4] = {}, c2[2][2][4] = {};
    __syncthreads();

    for (int it = 0; it <= nsteps; ++it) {
      const int tp = it - 1;
      wait_team(fb, (it >= T_SEQ) ? it : it - 6, NEG, &sh_dead);

      // ---- LIN(tp): stage h3(tp) via 4 batched dwordx4/thread, then dot ----
      if (tp >= T_SEQ - 1) {
        const _Float16* src = h3b + (size_t)(tp & DMASK) * H3_SLOT;
        half8 tmp[4];
#pragma unroll
        for (int i = 0; i < 4; ++i) ldg16(&tmp[i], src + (tid + i*256)*8);
        drain();
#pragma unroll
        for (int i = 0; i < 4; ++i) {
          const int idx = tid + i*256;
          const int gl = idx >> 9, nn = (idx >> 5) & 15, c = (idx & 31) * 8;
          *(half8*)(&xh3ld[gl][nn][c]) = tmp[i];
        }
        __syncthreads();
        if (tid < 128) {
          const int kq = tid & 1, ch = (tid >> 1) & 1, nn = (tid >> 2) & 15, gl = (tid >> 6) & 1;
          float acc = 0.f;
#pragma unroll
          for (int i = 0; i < 56; ++i) {
            const int k = kq*224 + i*4;
            const half4 xv = (k < 192) ? *(const half4*)(&xh2s[gl][nn][k])
                                       : *(const half4*)(&xh3ld[gl][nn][k - 192]);
            const float* wl = &wlin[ch][k];
            acc = fmaf(wl[0], (float)xv[0], acc);
            acc = fmaf(wl[1], (float)xv[1], acc);
            acc = fmaf(wl[2], (float)xv[2], acc);
            acc = fmaf(wl[3], (float)xv[3], acc);
          }
          acc += __shfl_xor(acc, 1, 64);
          if (kq == 0) {
            const float o = acc + blin[ch];
            out[((size_t)(b0 + gl*16 + nn)*fut + (tp - (T_SEQ - 1)))*2 + ch] = o;
            xh1s[gl][nn][64 + ch] = (_Float16)o;
          }
        }
      }
      if (it < T_SEQ && tid < 64) {
        const int gl = tid >> 5, nn = (tid >> 1) & 15, ch = tid & 1;
        xh1s[gl][nn][64 + ch] =
            (_Float16)input[((size_t)(b0 + gl*16 + nn)*T_SEQ + it)*2 + ch];
      }
      __syncthreads();
      if (it == nsteps) break;

      // ---- L1(it) ----
      half8 bf1[2][3];
#pragma unroll
      for (int g = 0; g < 2; ++g)
#pragma unroll
        for (int kk = 0; kk < 3; ++kk)
          bf1[g][kk] = *(const half8*)(&xh1s[g][n][kk*32 + l4*8]);
      __syncthreads();
#pragma unroll
      for (int g = 0; g < 2; ++g) {
        f32x4 acc[4];
#pragma unroll
        for (int q = 0; q < 4; ++q)
#pragma unroll
          for (int e = 0; e < 4; ++e) acc[q][e] = b1r[q][e];
#pragma unroll
        for (int q = 0; q < 4; ++q)
#pragma unroll
          for (int kk = 0; kk < 3; ++kk)
            acc[q] = __builtin_amdgcn_mfma_f32_16x16x32_f16(a1[q][kk], bf1[g][kk], acc[q], 0, 0, 0);
        half4 hv;
#pragma unroll
        for (int e = 0; e < 4; ++e) {
          const float cn = sigm(acc[1][e]) * c1[g][e] + sigm(acc[0][e]) * tanh_fast(acc[2][e]);
          const float h = sigm(acc[3][e]) * tanh_fast(cn);
          c1[g][e] = cn;
          hv[e] = (_Float16)h;
        }
        *(half4*)(&xh1s[g][n][w*16 + l4*4]) = hv;
        *(half4*)(&xh2s[g][n][w*16 + l4*4]) = hv;
      }
      __syncthreads();

      // ---- L2(it) ----
      half8 bf2[2][6];
#pragma unroll
      for (int g = 0; g < 2; ++g)
#pragma unroll
        for (int kk = 0; kk < 6; ++kk)
          bf2[g][kk] = *(const half8*)(&xh2s[g][n][kk*32 + l4*8]);
      __syncthreads();
      const int slot = it & DMASK;
#pragma unroll
      for (int u = 0; u < 2; ++u)
#pragma unroll
        for (int g = 0; g < 2; ++g) {
          f32x4 acc[4];
#pragma unroll
          for (int q = 0; q < 4; ++q)
#pragma unroll
            for (int e = 0; e < 4; ++e) acc[q][e] = b2r[u][q][e];
#pragma unroll
          for (int q = 0; q < 4; ++q)
#pragma unroll
            for (int kk = 0; kk < 6; ++kk)
              acc[q] = __builtin_amdgcn_mfma_f32_16x16x32_f16(a2[u][q][kk], bf2[g][kk], acc[q], 0, 0, 0);
          half4 hv;
#pragma unroll
          for (int e = 0; e < 4; ++e) {
            const float cn = sigm(acc[1][e]) * c2[u][g][e] + sigm(acc[0][e]) * tanh_fast(acc[2][e]);
            const float h = sigm(acc[3][e]) * tanh_fast(cn);
            c2[u][g][e] = cn;
            hv[e] = (_Float16)h;
          }
          const int row = (u*4 + w)*16 + l4*4;
          *(half4*)(&xh2s[g][n][64 + row]) = hv;
          stg8(h2b + (size_t)slot*H2_SLOT + g*H2_G + n*128 + row, hv);
        }
      asm volatile("s_waitcnt vmcnt(0)" ::: "memory");
      __syncthreads();
      if (tid == 0) stflag(fb + 4*64, it + 1);
    }
  } else {
    // =================== L3 quarter (1 tile/wave) ===================
    const int slice = role - 1;          // 0..3
    const int tl = slice*4 + w;          // tile 0..15
    half8 a3[4][12];
#pragma unroll
    for (int q = 0; q < 4; ++q)
#pragma unroll
      for (int kk = 0; kk < 12; ++kk)
        a3[q][kk] = *(const half8*)(WT + WSZ1 + WSZ2 + ((q*NJT3 + tl)*NKB3 + kk)*512 + lane*8);
    float b3r[4][4];
#pragma unroll
    for (int q = 0; q < 4; ++q)
#pragma unroll
      for (int e = 0; e < 4; ++e) {
        const int r = q*256 + tl*16 + l4*4 + e;
        b3r[q][e] = bih3[r] + bhh3[r];
      }
    float c3[2][4] = {};
    __syncthreads();

    for (int t = 0; t < nsteps; ++t) {
      wait_team(fb, t, t + 1, &sh_dead);  // fl3 >= t (h3(t-1)), flf >= t+1 (h2(t))
      const int slot = t & DMASK, slot1 = (t - 1) & DMASK;
      half8 bf[2][12];
      // batched issue: all 24 dwordx4 in flight, ONE drain
#pragma unroll
      for (int g = 0; g < 2; ++g) {
        const _Float16* h2p = h2b + (size_t)slot*H2_SLOT + g*H2_G + n*128;
#pragma unroll
        for (int kk = 0; kk < 4; ++kk) ldg16(&bf[g][kk], h2p + kk*32 + l4*8);
      }
      if (t > 0) {
#pragma unroll
        for (int g = 0; g < 2; ++g) {
          const _Float16* h3p = h3b + (size_t)slot1*H3_SLOT + g*H3_G + n*256;
#pragma unroll
          for (int kk = 4; kk < 12; ++kk) ldg16(&bf[g][kk], h3p + (kk-4)*32 + l4*8);
        }
      } else {
#pragma unroll
        for (int g = 0; g < 2; ++g)
#pragma unroll
          for (int kk = 4; kk < 12; ++kk) bf[g][kk] = half8{};
      }
      drain();
#pragma unroll
      for (int g = 0; g < 2; ++g) {
        f32x4 acc[4];
#pragma unroll
        for (int q = 0; q < 4; ++q)
#pragma unroll
          for (int e = 0; e < 4; ++e) acc[q][e] = b3r[q][e];
#pragma unroll
        for (int q = 0; q < 4; ++q)
#pragma unroll
          for (int kk = 0; kk < 12; ++kk)
            acc[q] = __builtin_amdgcn_mfma_f32_16x16x32_f16(a3[q][kk], bf[g][kk], acc[q], 0, 0, 0);
        half4 hv;
#pragma unroll
        for (int e = 0; e < 4; ++e) {
          const float cn = sigm(acc[1][e]) * c3[g][e] + sigm(acc[0][e]) * tanh_fast(acc[2][e]);
          const float h = sigm(acc[3][e]) * tanh_fast(cn);
          c3[g][e] = cn;
          hv[e] = (_Float16)h;
        }
        stg8(h3b + (size_t)slot*H3_SLOT + g*H3_G + n*256 + tl*16 + l4*4, hv);
      }
      asm volatile("s_waitcnt vmcnt(0)" ::: "memory");
      __syncthreads();
      if (tid == 0) stflag(fb + slice*64, t + 1);
    }
  }
}

extern "C" void kernel_launch(void* const* d_in, const int* in_sizes, int n_in,
                              void* d_out, int out_size, void* d_ws, size_t ws_size,
                              hipStream_t stream) {
  const float* input = (const float*)d_in[0];
  const int*   fut   = (const int*)d_in[1];
  const float* Wih1  = (const float*)d_in[2];
  const float* Whh1  = (const float*)d_in[3];
  const float* bih1  = (const float*)d_in[4];
  const float* bhh1  = (const float*)d_in[5];
  const float* Wih2  = (const float*)d_in[6];
  const float* Whh2  = (const float*)d_in[7];
  const float* bih2  = (const float*)d_in[8];
  const float* bhh2  = (const float*)d_in[9];
  const float* Wih3  = (const float*)d_in[10];
  const float* Whh3  = (const float*)d_in[11];
  const float* bih3  = (const float*)d_in[12];
  const float* bhh3  = (const float*)d_in[13];
  const float* Wlin  = (const float*)d_in[14];
  const float* blin  = (const float*)d_in[15];
  float* out = (float*)d_out;

  _Float16* WT  = (_Float16*)d_ws;
  _Float16* h2r = WT + WTOT;
  _Float16* h3r = h2r + (size_t)NTEAM * H2_TEAM;
  int* flags    = (int*)(h3r + (size_t)NTEAM * H3_TEAM);
  const size_t flag_bytes = (size_t)NTEAM * 512 * sizeof(int);

  prep_weights<<<(WTOT + 255) / 256, 256, 0, stream>>>(Wih1, Whh1, Wih2, Whh2, Wih3, Whh3, WT);
  hipMemsetAsync(flags, 0, flag_bytes, stream);
  pipe_main<<<5 * NTEAM, 256, 0, stream>>>(input, fut,
                                           bih1, bhh1, bih2, bhh2, bih3, bhh3,
                                           Wlin, blin, WT, h2r, h3r, flags, out);
}